// Round 8
// baseline (514.483 us; speedup 1.0000x reference)
//
#include <hip/hip_runtime.h>
#include <math.h>

#define B_ 16
#define N_ 4096
#define M_ 1024
#define C1_ 256
#define C2_ 512
#define H_ 256
#define SEC_ 10
#define BN_EPS 1e-5f

typedef _Float16 f16;
typedef f16 f16x8 __attribute__((ext_vector_type(8)));
typedef f16 f16x4 __attribute__((ext_vector_type(4)));
typedef float f32x4 __attribute__((ext_vector_type(4)));

// ---------------------------------------------------------------------------
// Prep A: convert W1 (256x768) and W2 (256x256) fp32 -> fp16, flat.
// ---------------------------------------------------------------------------
__global__ __launch_bounds__(256)
void conv_weights_kernel(const float* __restrict__ W1, const float* __restrict__ W2,
                         f16* __restrict__ W1h, f16* __restrict__ W2h)
{
    const int i = (blockIdx.x*256 + threadIdx.x)*4;       // 262144 total
    const int n1 = H_*(C1_+C2_);                          // 196608
    if (i < n1) {
        const float4 v = *(const float4*)(W1 + i);
        f16x4 o; o[0]=(f16)v.x; o[1]=(f16)v.y; o[2]=(f16)v.z; o[3]=(f16)v.w;
        *(f16x4*)(W1h + i) = o;
    } else {
        const int j = i - n1;
        const float4 v = *(const float4*)(W2 + j);
        f16x4 o; o[0]=(f16)v.x; o[1]=(f16)v.y; o[2]=(f16)v.z; o[3]=(f16)v.w;
        *(f16x4*)(W2h + j) = o;
    }
}

// ---------------------------------------------------------------------------
// Prep B: transpose+convert fp32 [C][Nsrc] (n-contig) -> fp16 [n][dstStride]
// (k-contig). Tile: 64 n x 256 c. c0 = blockIdx.y*256 handles C2=512 case.
// ---------------------------------------------------------------------------
__global__ __launch_bounds__(256)
void transpose_cvt_kernel(const float* __restrict__ src, f16* __restrict__ dst,
                          int Nsrc, int dstStride, long srcBS, long dstBS)
{
    __shared__ __align__(16) f16 T[64*264];
    const int b  = blockIdx.z;
    const int c0 = blockIdx.y*256;
    const int n0 = blockIdx.x*64;
    const int t  = threadIdx.x;
    // read: thread t = channel row c, 64 n values
    {
        const float* s = src + (long)b*srcBS + (long)(c0 + t)*Nsrc + n0;
        #pragma unroll
        for (int i = 0; i < 16; i++) {
            const float4 v = *(const float4*)(s + i*4);
            T[(i*4+0)*264 + t] = (f16)v.x;
            T[(i*4+1)*264 + t] = (f16)v.y;
            T[(i*4+2)*264 + t] = (f16)v.z;
            T[(i*4+3)*264 + t] = (f16)v.w;
        }
    }
    __syncthreads();
    // write: thread t -> n = t>>2, 64-half chunk ch = t&3
    const int n = t >> 2, ch = t & 3;
    f16* d = dst + (long)b*dstBS + (long)(n0 + n)*dstStride + c0 + ch*64;
    #pragma unroll
    for (int i = 0; i < 8; i++)
        *(f16x8*)(d + i*8) = *(const f16x8*)&T[n*264 + ch*64 + i*8];
}

// ---------------------------------------------------------------------------
// K1: three_nn v4 (unchanged — passed R6)
// ---------------------------------------------------------------------------
__global__ __launch_bounds__(256)
void three_nn_kernel(const float* __restrict__ unknown, const float* __restrict__ known,
                     int* __restrict__ idxp, float* __restrict__ wgtp)
{
    __shared__ float kx[M_], ky[M_], kz[M_];
    __shared__ float cd[4][64][3];
    __shared__ int   ci[4][64][3];
    const int b  = blockIdx.y;
    const int bn = blockIdx.x * 64;
    const int t  = threadIdx.x;
    const float* kb = known + (long)b * M_ * 3;
    {
        const float4 q0 = *(const float4*)(kb + 12*t);
        const float4 q1 = *(const float4*)(kb + 12*t + 4);
        const float4 q2 = *(const float4*)(kb + 12*t + 8);
        const int m = 4*t;
        kx[m+0]=q0.x; ky[m+0]=q0.y; kz[m+0]=q0.z;
        kx[m+1]=q0.w; ky[m+1]=q1.x; kz[m+1]=q1.y;
        kx[m+2]=q1.z; ky[m+2]=q1.w; kz[m+2]=q2.x;
        kx[m+3]=q2.y; ky[m+3]=q2.z; kz[m+3]=q2.w;
    }
    __syncthreads();
    const int w = t >> 6, ln = t & 63;
    const int n = bn + ln;
    const float* up = unknown + ((long)b * N_ + n) * 3;
    const float ux = up[0], uy = up[1], uz = up[2];
    float b0 = 1e30f, b1v = 1e30f, b2v = 1e30f;
    int j0 = 0, j1 = 0, j2 = 0;
    const int m0 = w * 256;
    for (int m = m0; m < m0 + 256; m += 4) {
        const float4 X = *(const float4*)&kx[m];
        const float4 Y = *(const float4*)&ky[m];
        const float4 Z = *(const float4*)&kz[m];
        const float px[4] = {X.x, X.y, X.z, X.w};
        const float py[4] = {Y.x, Y.y, Y.z, Y.w};
        const float pz[4] = {Z.x, Z.y, Z.z, Z.w};
        #pragma unroll
        for (int q = 0; q < 4; q++) {
            const float dx = ux - px[q], dy = uy - py[q], dz = uz - pz[q];
            const float d = dx*dx + dy*dy + dz*dz;
            if (d < b2v) {
                const int mm = m + q;
                if (d < b1v) {
                    b2v = b1v; j2 = j1;
                    if (d < b0) { b1v = b0; j1 = j0; b0 = d; j0 = mm; }
                    else        { b1v = d;  j1 = mm; }
                } else { b2v = d; j2 = mm; }
            }
        }
    }
    cd[w][ln][0] = b0;  cd[w][ln][1] = b1v; cd[w][ln][2] = b2v;
    ci[w][ln][0] = j0;  ci[w][ln][1] = j1;  ci[w][ln][2] = j2;
    __syncthreads();
    if (t < 64) {
        float d0 = cd[0][t][0], d1 = cd[0][t][1], d2 = cd[0][t][2];
        int   i0 = ci[0][t][0], i1 = ci[0][t][1], i2 = ci[0][t][2];
        #pragma unroll
        for (int c = 1; c < 4; c++) {
            #pragma unroll
            for (int j = 0; j < 3; j++) {
                const float d = cd[c][t][j];
                const int  ix = ci[c][t][j];
                if (d < d2) {
                    if (d < d1) {
                        d2 = d1; i2 = i1;
                        if (d < d0) { d1 = d0; i1 = i0; d0 = d; i0 = ix; }
                        else        { d1 = d;  i1 = ix; }
                    } else { d2 = d; i2 = ix; }
                }
            }
        }
        const float r0 = 1.f/(d0 + 1e-8f), r1 = 1.f/(d1 + 1e-8f), r2 = 1.f/(d2 + 1e-8f);
        const float rs = 1.f/(r0 + r1 + r2);
        const long base = ((long)b * N_ + bn + t) * 3;
        idxp[base+0] = i0; idxp[base+1] = i1; idxp[base+2] = i2;
        wgtp[base+0] = r0*rs; wgtp[base+1] = r1*rs; wgtp[base+2] = r2*rs;
    }
}

// ---------------------------------------------------------------------------
// fp16-MFMA GEMM, barrier-free K-loop.
// BM=256 (all output rows) x BN=64; K panels of 256 (KHN panels).
// B panel (64 x 256 fp16, k-contig source) staged ONCE per panel (1 barrier).
// A tiles are wave-private (wave w owns rows w*64..+63): staged into per-wave
// LDS region with register prefetch — no __syncthreads in the K-loop.
// MODE 0: n-major store (Gt).  MODE 1: interp(Gt) + stats + n-major store
// (h1t). MODE 2: stats + fp32 h-major store (pre-BN2 -> d_out).
// LDS: Bsh 64x264 (33792 B) + Aw 4x64x40 (20480 B) = 54272 B -> 3 blocks/CU.
// P (64x264, epilogue) aliases Bsh.
// ---------------------------------------------------------------------------
template<int MODE, int KHN>
__global__ __launch_bounds__(256)
void gemm_mfma2(const f16* __restrict__ A, int lda,
                const f16* __restrict__ Bt, int ldb,
                f16* __restrict__ Ct, float* __restrict__ outf,
                const f16* __restrict__ Gt,
                const int* __restrict__ idxp, const float* __restrict__ wgtp,
                float* __restrict__ psum)
{
    static __shared__ __align__(16) char smem[54272];
    f16* Bsh = (f16*)smem;                 // [64][264]
    f16* Aw  = (f16*)(smem + 33792);       // 4 waves x [64][40]
    f16* P   = (f16*)smem;                 // epilogue alias of Bsh

    const int b   = blockIdx.y;
    const int bn  = blockIdx.x * 64;
    const int tid = threadIdx.x;
    const int l = tid & 63, w = tid >> 6;
    const int lane16 = l & 15, quad = l >> 4;
    const long nrows = (long)gridDim.x * 64;

    const f16* Bb = Bt + (long)b * nrows * ldb;

    f32x4 acc[4][4];
    #pragma unroll
    for (int i = 0; i < 4; i++)
        #pragma unroll
        for (int j = 0; j < 4; j++)
            acc[i][j] = (f32x4){0.f, 0.f, 0.f, 0.f};

    const int sn = tid >> 2, sc = tid & 3;

    for (int kh = 0; kh < KHN; kh++) {
        __syncthreads();
        {
            const f16* s = Bb + (long)(bn + sn)*ldb + kh*256 + sc*64;
            f16* d = Bsh + sn*264 + sc*64;
            #pragma unroll
            for (int i = 0; i < 8; i++)
                *(f16x8*)(d + i*8) = *(const f16x8*)(s + i*8);
        }
        __syncthreads();
        const f16* Arow = A + (long)(w*64 + l)*lda + kh*256;
        f16* Adst = Aw + w*2560 + l*40;
        f16x8 areg[4];
        #pragma unroll
        for (int c = 0; c < 4; c++) areg[c] = *(const f16x8*)(Arow + c*8);
        #pragma unroll
        for (int kc = 0; kc < 8; kc++) {
            #pragma unroll
            for (int c = 0; c < 4; c++) *(f16x8*)(Adst + c*8) = areg[c];
            if (kc < 7) {
                #pragma unroll
                for (int c = 0; c < 4; c++)
                    areg[c] = *(const f16x8*)(Arow + (kc+1)*32 + c*8);
            }
            f16x8 af[4], bf[4];
            #pragma unroll
            for (int i = 0; i < 4; i++)
                af[i] = *(const f16x8*)&Aw[w*2560 + (i*16 + lane16)*40 + quad*8];
            #pragma unroll
            for (int j = 0; j < 4; j++)
                bf[j] = *(const f16x8*)&Bsh[(j*16 + lane16)*264 + kc*32 + quad*8];
            #pragma unroll
            for (int i = 0; i < 4; i++)
                #pragma unroll
                for (int j = 0; j < 4; j++)
                    acc[i][j] = __builtin_amdgcn_mfma_f32_16x16x32_f16(af[i], bf[j], acc[i][j], 0, 0, 0);
        }
    }

    // ---------------- epilogue ----------------
    __syncthreads();   // K-loop reads of Bsh done; P (alias) becomes writable

    if constexpr (MODE == 0) {
        #pragma unroll
        for (int i = 0; i < 4; i++)
            #pragma unroll
            for (int r = 0; r < 4; r++) {
                const int row = w*64 + i*16 + quad*4 + r;
                #pragma unroll
                for (int j = 0; j < 4; j++)
                    P[(j*16 + lane16)*264 + row] = (f16)acc[i][j][r];
            }
        __syncthreads();
        const int n = tid >> 2, ch = tid & 3;
        f16* d = Ct + ((long)b*nrows + bn + n)*256 + ch*64;
        #pragma unroll
        for (int i = 0; i < 8; i++)
            *(f16x8*)(d + i*8) = *(const f16x8*)&P[n*264 + ch*64 + i*8];
    } else if constexpr (MODE == 1) {
        // P := interp from Gt (coalesced 3-row gather per point)
        {
            const int p  = tid >> 2;
            const int qd = tid & 3;
            const long ib = ((long)b*N_ + bn + p)*3;
            const int i0 = idxp[ib], i1 = idxp[ib+1], i2 = idxp[ib+2];
            const float w0 = wgtp[ib], w1 = wgtp[ib+1], w2 = wgtp[ib+2];
            const f16* gb = Gt + (long)b*M_*H_;
            const f16* g0 = gb + (long)i0*H_ + qd*64;
            const f16* g1 = gb + (long)i1*H_ + qd*64;
            const f16* g2 = gb + (long)i2*H_ + qd*64;
            f16* Pr = P + p*264 + qd*64;
            #pragma unroll
            for (int c = 0; c < 64; c += 8) {
                const f16x8 x0 = *(const f16x8*)&g0[c];
                const f16x8 x1 = *(const f16x8*)&g1[c];
                const f16x8 x2 = *(const f16x8*)&g2[c];
                f16x8 o;
                #pragma unroll
                for (int e = 0; e < 8; e++)
                    o[e] = (f16)(w0*(float)x0[e] + w1*(float)x1[e] + w2*(float)x2[e]);
                *(f16x8*)&Pr[c] = o;
            }
        }
        __syncthreads();
        // acc += P (in LDS, final h1) + per-h stats
        const int bid = blockIdx.y*gridDim.x + blockIdx.x;
        float* ps = psum + (long)bid * (2*H_);
        #pragma unroll
        for (int i = 0; i < 4; i++)
            #pragma unroll
            for (int r = 0; r < 4; r++) {
                const int row = w*64 + i*16 + quad*4 + r;
                float s1 = 0.f, s2 = 0.f;
                #pragma unroll
                for (int j = 0; j < 4; j++) {
                    const int idx = (j*16 + lane16)*264 + row;
                    const float v = acc[i][j][r] + (float)P[idx];
                    P[idx] = (f16)v;
                    s1 += v; s2 += v*v;
                }
                #pragma unroll
                for (int off = 1; off < 16; off <<= 1) {
                    s1 += __shfl_xor(s1, off, 64);
                    s2 += __shfl_xor(s2, off, 64);
                }
                if (lane16 == 0) { ps[row] = s1; ps[H_ + row] = s2; }
            }
        __syncthreads();
        const int n = tid >> 2, ch = tid & 3;
        f16* d = Ct + ((long)b*N_ + bn + n)*256 + ch*64;
        #pragma unroll
        for (int i = 0; i < 8; i++)
            *(f16x8*)(d + i*8) = *(const f16x8*)&P[n*264 + ch*64 + i*8];
    } else {
        // MODE 2: fp32 h-major store (pre-BN2) + stats
        const int bid = blockIdx.y*gridDim.x + blockIdx.x;
        float* ps = psum + (long)bid * (2*H_);
        float* Ob = outf + (long)b*H_*N_;
        #pragma unroll
        for (int i = 0; i < 4; i++)
            #pragma unroll
            for (int r = 0; r < 4; r++) {
                const int row = w*64 + i*16 + quad*4 + r;
                float s1 = 0.f, s2 = 0.f;
                #pragma unroll
                for (int j = 0; j < 4; j++) {
                    const float v = acc[i][j][r];
                    Ob[(long)row*N_ + bn + j*16 + lane16] = v;
                    s1 += v; s2 += v*v;
                }
                #pragma unroll
                for (int off = 1; off < 16; off <<= 1) {
                    s1 += __shfl_xor(s1, off, 64);
                    s2 += __shfl_xor(s2, off, 64);
                }
                if (lane16 == 0) { ps[row] = s1; ps[H_ + row] = s2; }
            }
    }
}

// ---------------------------------------------------------------------------
__global__ __launch_bounds__(256)
void reduce_stats_kernel(const float* __restrict__ psum, float* __restrict__ stats, int nblk)
{
    __shared__ float red[8][33];
    const int o  = blockIdx.x*32 + (threadIdx.x & 31);
    const int ch = threadIdx.x >> 5;
    float s = 0.f;
    for (int bid = ch; bid < nblk; bid += 8)
        s += psum[(long)bid*(2*H_) + o];
    red[ch][threadIdx.x & 31] = s;
    __syncthreads();
    if (ch == 0) {
        float t = 0.f;
        #pragma unroll
        for (int c = 0; c < 8; c++) t += red[c][threadIdx.x & 31];
        stats[o] = t;
    }
}

// ---------------------------------------------------------------------------
// finalize1: BN1 params; rw2h = fp16 [16][256] (rows 10..15 zero) for se_mfma;
// rbAdj[j] = se_rb[j] + sum_o se_rw[j][o]*c1[o]
// ---------------------------------------------------------------------------
__global__ __launch_bounds__(256)
void finalize1_kernel(const float* __restrict__ stats,
                      const float* __restrict__ g, const float* __restrict__ bb,
                      const float* __restrict__ se_rw, const float* __restrict__ se_rb,
                      float* __restrict__ a1, float* __restrict__ c1,
                      f16* __restrict__ rw2h, float* __restrict__ rbAdj)
{
    __shared__ float cbuf[H_];
    __shared__ float red[256];
    const int o = threadIdx.x;
    const float inv = 1.f / (float)(B_ * N_);
    const float S1 = stats[o], S2 = stats[H_ + o];
    const float mean = S1 * inv;
    const float var  = S2 * inv - mean*mean;
    const float a = g[o] * rsqrtf(var + BN_EPS);
    const float c = bb[o] - mean*a;
    a1[o] = a; c1[o] = c; cbuf[o] = c;
    for (int j = 0; j < SEC_; j++) rw2h[j*H_ + o] = (f16)(se_rw[j*H_ + o] * a);
    for (int j = SEC_; j < 16; j++) rw2h[j*H_ + o] = (f16)0.f;
    __syncthreads();
    for (int j = 0; j < SEC_; j++) {
        red[o] = se_rw[j*H_ + o] * cbuf[o];
        __syncthreads();
        for (int s = 128; s > 0; s >>= 1) {
            if (o < s) red[o] += red[o + s];
            __syncthreads();
        }
        if (o == 0) rbAdj[j] = se_rb[j] + red[0];
        __syncthreads();
    }
}

// ---------------------------------------------------------------------------
// SE reduce as skinny MFMA: s[16][n]; writes swish(s+rbAdj) for j<10.
// One 16x16 tile per wave, K=256.
// ---------------------------------------------------------------------------
__global__ __launch_bounds__(256)
void se_mfma_kernel(const f16* __restrict__ h1t, const f16* __restrict__ rw2h,
                    const float* __restrict__ rbAdj, float* __restrict__ ssw)
{
    const int b = blockIdx.y, bn = blockIdx.x*64;
    const int t = threadIdx.x, w = t >> 6, l = t & 63;
    const int lane16 = l & 15, quad = l >> 4;
    const int n0 = bn + w*16;
    f32x4 acc = (f32x4){0.f,0.f,0.f,0.f};
    const f16* hb = h1t + ((long)b*N_ + n0 + lane16)*256;
    #pragma unroll
    for (int kc = 0; kc < 8; kc++) {
        const f16x8 a  = *(const f16x8*)&rw2h[lane16*256 + kc*32 + quad*8];
        const f16x8 bf = *(const f16x8*)&hb[kc*32 + quad*8];
        acc = __builtin_amdgcn_mfma_f32_16x16x32_f16(a, bf, acc, 0, 0, 0);
    }
    const int nn = n0 + lane16;
    #pragma unroll
    for (int r = 0; r < 4; r++) {
        const int j = quad*4 + r;
        if (j < SEC_) {
            const float s = acc[r] + rbAdj[j];
            ssw[((long)b*N_ + nn)*SEC_ + j] = s / (1.f + __expf(-s));
        }
    }
}

// ---------------------------------------------------------------------------
// h1g: in-place SE gate on h1t: h1t[n][k] = sigmoid(eb[k]+ew[k]·ssw[n]) *
// (a1[k]*h1t[n][k] + c1[k]).  2 threads per n (128-k halves).
// ---------------------------------------------------------------------------
__global__ __launch_bounds__(256)
void h1g_kernel(f16* __restrict__ h1t, const float* __restrict__ ssw,
                const float* __restrict__ se_ew, const float* __restrict__ se_eb,
                const float* __restrict__ a1, const float* __restrict__ c1)
{
    const int t = threadIdx.x;
    const long n = (long)blockIdx.x*128 + (t & 127);
    const int half = t >> 7;
    float sswr[SEC_];
    #pragma unroll
    for (int j = 0; j < SEC_; j++) sswr[j] = ssw[n*SEC_ + j];
    f16* row = h1t + n*256 + half*128;
    #pragma unroll
    for (int i = 0; i < 16; i++) {
        f16x8 h = *(f16x8*)&row[i*8];
        f16x8 o;
        #pragma unroll
        for (int e = 0; e < 8; e++) {
            const int k = half*128 + i*8 + e;
            float ev = se_eb[k];
            #pragma unroll
            for (int j = 0; j < SEC_; j++) ev += se_ew[k*SEC_ + j]*sswr[j];
            const float gg = 1.f/(1.f + __expf(-ev));
            o[e] = (f16)(gg*(a1[k]*(float)h[e] + c1[k]));
        }
        *(f16x8*)&row[i*8] = o;
    }
}

__global__ __launch_bounds__(256)
void finalize2_kernel(const float* __restrict__ stats,
                      const float* __restrict__ g, const float* __restrict__ bb,
                      float* __restrict__ a2, float* __restrict__ c2)
{
    const int o = threadIdx.x;
    const float inv = 1.f / (float)(B_ * N_);
    const float S1 = stats[o], S2 = stats[H_ + o];
    const float mean = S1 * inv;
    const float var  = S2 * inv - mean*mean;
    const float a = g[o] * rsqrtf(var + BN_EPS);
    a2[o] = a; c2[o] = bb[o] - mean*a;
}

// in-place BN2 + ReLU on fp32 d_out
__global__ __launch_bounds__(256)
void bn_relu_kernel(float* __restrict__ out, const float* __restrict__ a2,
                    const float* __restrict__ c2)
{
    const long e = ((long)blockIdx.x*256 + threadIdx.x)*4;
    const int o = (int)((e >> 12) & (H_ - 1));
    float4 v = *(float4*)(out + e);
    const float a = a2[o], c = c2[o];
    v.x = fmaxf(a*v.x + c, 0.f);
    v.y = fmaxf(a*v.y + c, 0.f);
    v.z = fmaxf(a*v.z + c, 0.f);
    v.w = fmaxf(a*v.w + c, 0.f);
    *(float4*)(out + e) = v;
}

// ---------------------------------------------------------------------------
extern "C" void kernel_launch(void* const* d_in, const int* in_sizes, int n_in,
                              void* d_out, int out_size, void* d_ws, size_t ws_size,
                              hipStream_t stream)
{
    const float* unknown = (const float*)d_in[0];
    const float* known   = (const float*)d_in[1];
    const float* uf      = (const float*)d_in[2];
    const float* kf      = (const float*)d_in[3];
    const float* W1      = (const float*)d_in[4];
    const float* g1      = (const float*)d_in[5];
    const float* b1      = (const float*)d_in[6];
    const float* se_rw   = (const float*)d_in[7];
    const float* se_rb   = (const float*)d_in[8];
    const float* se_ew   = (const float*)d_in[9];
    const float* se_eb   = (const float*)d_in[10];
    const float* W2      = (const float*)d_in[11];
    const float* g2      = (const float*)d_in[12];
    const float* b2      = (const float*)d_in[13];

    char* ws = (char*)d_ws;
    size_t off = 0;
    auto alloc = [&](size_t bytes) -> void* {
        void* p = ws + off;
        off += (bytes + 255) & ~(size_t)255;
        return p;
    };
    const int NBLK = (N_/64) * B_;                              // 1024
    int*   idxp   = (int*)  alloc((size_t)B_*N_*3*4);
    float* wgtp   = (float*)alloc((size_t)B_*N_*3*4);
    f16*   W1h    = (f16*)  alloc((size_t)H_*(C1_+C2_)*2);
    f16*   W2h    = (f16*)  alloc((size_t)H_*H_*2);
    f16*   uft    = (f16*)  alloc((size_t)B_*N_*C1_*2);         // 33.5 MB [b][n][c1]
    f16*   kft    = (f16*)  alloc((size_t)B_*M_*C2_*2);         // 16.8 MB [b][m][c2]
    f16*   Gt     = (f16*)  alloc((size_t)B_*M_*H_*2);          // 8.4 MB  [b][m][h]
    f16*   h1t    = (f16*)  alloc((size_t)B_*N_*H_*2);          // 33.5 MB [b][n][h], gated in-place
    float* ssw    = (float*)alloc((size_t)B_*N_*SEC_*4);        // 2.6 MB
    float* psum1  = (float*)alloc((size_t)NBLK*2*H_*4);
    float* psum2  = (float*)alloc((size_t)NBLK*2*H_*4);
    float* stats1 = (float*)alloc(2*H_*4);
    float* stats2 = (float*)alloc(2*H_*4);
    float* a1     = (float*)alloc(H_*4);
    float* c1     = (float*)alloc(H_*4);
    f16*   rw2h   = (f16*)  alloc(16*H_*2);
    float* rbAdj  = (float*)alloc(64*4);
    float* a2     = (float*)alloc(H_*4);
    float* c2     = (float*)alloc(H_*4);
    (void)ws_size; (void)in_sizes; (void)n_in; (void)out_size;

    float* out = (float*)d_out;

    // prep
    conv_weights_kernel<<<dim3(256), 256, 0, stream>>>(W1, W2, W1h, W2h);
    transpose_cvt_kernel<<<dim3(N_/64, 1, B_), 256, 0, stream>>>(
        uf, uft, N_, C1_, (long)C1_*N_, (long)N_*C1_);
    transpose_cvt_kernel<<<dim3(M_/64, 2, B_), 256, 0, stream>>>(
        kf, kft, M_, C2_, (long)C2_*M_, (long)M_*C2_);

    // K1: three_nn
    three_nn_kernel<<<dim3(N_/64, B_), 256, 0, stream>>>(unknown, known, idxp, wgtp);

    // K2: Gt = (W1a @ kf)^T  (K=512 -> 2 panels)
    gemm_mfma2<0,2><<<dim3(M_/64, B_), 256, 0, stream>>>(
        W1h, C1_+C2_, kft, C2_, Gt, nullptr, nullptr, nullptr, nullptr, nullptr);

    // K3: h1t = (W1b @ uf)^T + interp(Gt); stats
    gemm_mfma2<1,1><<<dim3(N_/64, B_), 256, 0, stream>>>(
        W1h + C2_, C1_+C2_, uft, C1_, h1t, nullptr, Gt, idxp, wgtp, psum1);

    reduce_stats_kernel<<<dim3(16), 256, 0, stream>>>(psum1, stats1, NBLK);
    finalize1_kernel<<<1, 256, 0, stream>>>(stats1, g1, b1, se_rw, se_rb, a1, c1, rw2h, rbAdj);

    // K5: SE reduce via skinny MFMA -> ssw (swish applied)
    se_mfma_kernel<<<dim3(N_/64, B_), 256, 0, stream>>>(h1t, rw2h, rbAdj, ssw);

    // K5b: in-place SE gate on h1t
    h1g_kernel<<<dim3(B_*N_/128), 256, 0, stream>>>(h1t, ssw, se_ew, se_eb, a1, c1);

    // K6: conv2 -> pre-BN fp32 into d_out; stats
    gemm_mfma2<2,1><<<dim3(N_/64, B_), 256, 0, stream>>>(
        W2h, H_, h1t, H_, nullptr, out, nullptr, nullptr, nullptr, psum2);

    reduce_stats_kernel<<<dim3(16), 256, 0, stream>>>(psum2, stats2, NBLK);
    finalize2_kernel<<<1, 256, 0, stream>>>(stats2, g2, b2, a2, c2);

    // K8: in-place BN2 + ReLU
    bn_relu_kernel<<<dim3((unsigned)((long)B_*H_*N_/1024)), 256, 0, stream>>>(out, a2, c2);
}